// Round 6
// baseline (85.005 us; speedup 1.0000x reference)
//
#include <hip/hip_runtime.h>
#include <hip/hip_bf16.h>
#include <stdint.h>

#define DD 128
#define CC 16
#define NS 1600
#define QQ 32768
#define NBLK 64

typedef __attribute__((ext_vector_type(8))) short short8;  // 8 bf16
typedef __attribute__((ext_vector_type(4))) float f32x4;

__device__ inline short f2bf(float x) {
  union { float f; uint32_t u; } v; v.f = x;
  uint32_t r = (v.u + 0x7FFFu + ((v.u >> 16) & 1u)) >> 16;  // RNE
  return (short)r;
}

__device__ inline uint32_t pk2bf(float lo, float hi) {
  __hip_bfloat162 h = __float22bfloat162_rn(make_float2(lo, hi));  // lo->low16
  union { __hip_bfloat162 h2; uint32_t u; } v; v.h2 = h;
  return v.u;
}

// ---------------------------------------------------------------------------
// Kernel 1: per-block partial class sums. grid=64, block=256.
// ---------------------------------------------------------------------------
__global__ __launch_bounds__(256) void centers_partial(
    const float* __restrict__ sfi, const float* __restrict__ sf,
    const int* __restrict__ labels, float* __restrict__ partA,
    float* __restrict__ partB, float* __restrict__ pcnt) {
  __shared__ float accA[2][CC][DD];
  __shared__ float accB[2][CC][DD];
  __shared__ float cnt[2][CC];
  const int t = threadIdx.x;
  const int d = t & 127, s = t >> 7;
  for (int i = t; i < 2 * CC * DD; i += 256) {
    ((float*)accA)[i] = 0.f;
    ((float*)accB)[i] = 0.f;
  }
  if (t < 2 * CC) ((float*)cnt)[t] = 0.f;
  __syncthreads();

  const int base = blockIdx.x * (NS / NBLK);
  for (int i = s; i < NS / NBLK; i += 2) {
    const int r = base + i;
    const int lbl = labels[r];
    accA[s][lbl][d] += sfi[(size_t)r * DD + d];
    accB[s][lbl][d] += sf[(size_t)r * DD + d];
    if (d == 0) cnt[s][lbl] += 1.f;
  }
  __syncthreads();

  float* pa = partA + (size_t)blockIdx.x * (CC * DD);
  float* pb = partB + (size_t)blockIdx.x * (CC * DD);
  for (int i = t; i < CC * DD; i += 256) {
    pa[i] = ((float*)accA)[i] + ((float*)accA)[CC * DD + i];
    pb[i] = ((float*)accB)[i] + ((float*)accB)[CC * DD + i];
  }
  if (t < CC) pcnt[blockIdx.x * CC + t] = cnt[0][t] + cnt[1][t];
}

// ---------------------------------------------------------------------------
// Kernel 2: finalize centers + fused per-class weights in FRAGMENT order.
// 16B unit u within class c: u = w*256 + kb*64 + lane (w=0..7, kb=0..3)
//   holds WtT[j][e0..e0+7] bf16, j = w*16 + (lane&15), e0 = kb*32 + (lane>>4)*8
// grid=16 (c), block=256. (unchanged layout -- main depends on it)
// ---------------------------------------------------------------------------
__global__ __launch_bounds__(256) void build_wt_kernel(
    const float* __restrict__ W1, const float* __restrict__ partA,
    const float* __restrict__ partB, const float* __restrict__ pcnt,
    float* __restrict__ sg_out, short* __restrict__ WtTg) {
  __shared__ float sgc[DD], prc[DD];
  const int c = blockIdx.x, t = threadIdx.x;

  float cnt = 0.f;
  for (int b = 0; b < NBLK; ++b) cnt += pcnt[b * CC + c];
  cnt = fmaxf(cnt, 1.f);
  if (t < 128) {
    float a = 0.f;
    for (int b = 0; b < NBLK; ++b) a += partA[(size_t)b * (CC * DD) + c * DD + t];
    const float m = a / cnt;
    const float s = 1.f / (1.f + expf(-m));
    sgc[t] = s;
    sg_out[c * DD + t] = s;
  } else {
    const int d = t - 128;
    float a = 0.f;
    for (int b = 0; b < NBLK; ++b) a += partB[(size_t)b * (CC * DD) + c * DD + d];
    prc[d] = a / cnt;
  }
  __syncthreads();

  for (int it = 0; it < 8; ++it) {
    const int u = it * 256 + t;
    const int w_ = u >> 8;
    const int kb = (u >> 6) & 3;
    const int lane = u & 63;
    const int j = w_ * 16 + (lane & 15);
    const int e0 = kb * 32 + (lane >> 4) * 8;
    short8 r;
#pragma unroll
    for (int rr = 0; rr < 8; ++rr) {
      const int e = e0 + rr;
      float v = W1[e * DD + j] + sgc[e] * W1[(DD + e) * DD + j] +
                prc[e] * W1[2 * DD * DD + j];
      r[rr] = f2bf(v);
    }
    *(short8*)(WtTg + ((size_t)c * 2048 + u) * 8) = r;
  }
}

// ---------------------------------------------------------------------------
// Kernel 3: FUSED main. grid=512, block=512 (8 waves), 64 q/block, 2 blk/CU.
// Wave w: j rows [w*16,+16), all 64 q. Per class: 4 W loads (L2, reg-dbuf) +
// 16 MFMA + lane-local relu/W2 fold + ONE ds_write_b128 (4 qn partials).
// After each 8-class half: barrier, f32x4 tree-reduce over (w,l4) -> sigmoid
// -> w_lds[q][c]. Final: fused agg epilogue (reads qf/sg global, writes out).
// No shuffles, no w_ws, no separate agg kernel.
// ---------------------------------------------------------------------------
__global__ __launch_bounds__(512, 4) void main_kernel(
    const float* __restrict__ qf, const short* __restrict__ WtTg,
    const float* __restrict__ b1, const float* __restrict__ W2,
    const float* __restrict__ b2, const float* __restrict__ sg,
    float* __restrict__ out) {
  __shared__ __align__(16) char p_lds[65536];  // [8c][8w][64lane] f32x4(qn)
  __shared__ float w_lds[64][17];              // [q][c], padded

  const int tid = threadIdx.x;
  const int lane = tid & 63;
  const int w = tid >> 6;  // 0..7
  const int l15 = lane & 15, l4 = lane >> 4;
  const int qbase = blockIdx.x * 64;

  // ---- B fragments: load qf f32, convert to bf16 in-register ----
  short8 bq[4][4];
#pragma unroll
  for (int qn = 0; qn < 4; ++qn) {
    const float* qrow = qf + (size_t)(qbase + qn * 16 + l15) * DD;
#pragma unroll
    for (int kb = 0; kb < 4; ++kb) {
      const float* p0 = qrow + kb * 32 + l4 * 8;
      f32x4 f0 = *(const f32x4*)(p0);
      f32x4 f1 = *(const f32x4*)(p0 + 4);
      union { short8 s; uint32_t u[4]; } r;
      r.u[0] = pk2bf(f0[0], f0[1]);
      r.u[1] = pk2bf(f0[2], f0[3]);
      r.u[2] = pk2bf(f1[0], f1[1]);
      r.u[3] = pk2bf(f1[2], f1[3]);
      bq[qn][kb] = r.s;
    }
  }

  const f32x4 b1v = *(const f32x4*)(b1 + w * 16 + l4 * 4);
  const f32x4 w2v = *(const f32x4*)(W2 + w * 16 + l4 * 4);
  const float b2s = b2[0];

  const char* wbase = (const char*)WtTg + w * 4096 + lane * 16;

#define LOADW(dst, cls)                                                     \
  {                                                                         \
    _Pragma("unroll") for (int kb = 0; kb < 4; ++kb) dst[kb] =              \
        *(const short8*)(wbase + (size_t)(cls)*32768 + kb * 1024);          \
  }

  // fold partials for 4 qn -> one b128 LDS write, no shuffles
#define COMPUTE(wf, cls)                                                    \
  {                                                                         \
    f32x4 pv;                                                               \
    _Pragma("unroll") for (int qp = 0; qp < 2; ++qp) {                      \
      f32x4 a0 = b1v, a1 = b1v;                                             \
      _Pragma("unroll") for (int kb = 0; kb < 4; ++kb) {                    \
        a0 = __builtin_amdgcn_mfma_f32_16x16x32_bf16(wf[kb],                \
                                                     bq[2 * qp][kb], a0,    \
                                                     0, 0, 0);              \
        a1 = __builtin_amdgcn_mfma_f32_16x16x32_bf16(wf[kb],                \
                                                     bq[2 * qp + 1][kb],    \
                                                     a1, 0, 0, 0);          \
      }                                                                     \
      float p0 = 0.f, p1 = 0.f;                                             \
      _Pragma("unroll") for (int i = 0; i < 4; ++i) {                       \
        p0 += fmaxf(a0[i], 0.f) * w2v[i];                                   \
        p1 += fmaxf(a1[i], 0.f) * w2v[i];                                   \
      }                                                                     \
      pv[2 * qp] = p0;                                                      \
      pv[2 * qp + 1] = p1;                                                  \
    }                                                                       \
    *(f32x4*)(p_lds + (((cls)&7) * 8 + w) * 1024 + lane * 16) = pv;         \
  }

  // reduce one 8-class half: thread t<128 -> (c7 = t>>4, l15r = t&15)
#define REDUCE(hf)                                                          \
  {                                                                         \
    __syncthreads();                                                        \
    if (tid < 128) {                                                        \
      const int c7 = tid >> 4, lr = tid & 15;                               \
      f32x4 vacc = {0.f, 0.f, 0.f, 0.f};                                    \
      _Pragma("unroll") for (int wv = 0; wv < 8; ++wv)                      \
          _Pragma("unroll") for (int g = 0; g < 4; ++g) vacc +=             \
          *(const f32x4*)(p_lds + (c7 * 8 + wv) * 1024 + (g * 16 + lr) * 16);\
      _Pragma("unroll") for (int qn = 0; qn < 4; ++qn)                      \
          w_lds[qn * 16 + lr][(hf)*8 + c7] =                                \
              1.f / (1.f + __expf(-(vacc[qn] + b2s)));                      \
    }                                                                       \
    __syncthreads();                                                        \
  }

  short8 wfA[4], wfB[4];
  LOADW(wfA, 0);
#pragma unroll
  for (int cp = 0; cp < CC; cp += 2) {
    LOADW(wfB, cp + 1);
    COMPUTE(wfA, cp);
    if (cp + 2 < CC) LOADW(wfA, cp + 2);
    COMPUTE(wfB, cp + 1);
    if (cp == 6) REDUCE(0);
    if (cp == 14) REDUCE(1);
  }
#undef LOADW
#undef COMPUTE
#undef REDUCE

  // ---- fused agg epilogue: thread (s = t>>5, ec = t&31), 4 q-iters ----
  {
    const int s = tid >> 5;   // 0..15
    const int ec = tid & 31;  // e-chunk
    const int e0 = ec * 4;

    f32x4 sgv[16];
#pragma unroll
    for (int c = 0; c < 16; ++c) sgv[c] = *(const f32x4*)(sg + c * DD + e0);

#pragma unroll
    for (int qi = 0; qi < 4; ++qi) {
      const int ql = qi * 16 + s;
      const int q = qbase + ql;
      float wc[16];
      float Sv = 0.f;
#pragma unroll
      for (int c = 0; c < 16; ++c) {
        wc[c] = w_lds[ql][c];
        Sv += wc[c];
      }
      f32x4 sgw = {0.f, 0.f, 0.f, 0.f};
#pragma unroll
      for (int c = 0; c < 16; ++c) sgw += wc[c] * sgv[c];

      const float* qrow = qf + (size_t)q * DD;
      f32x4 qa = *(const f32x4*)(qrow + e0);
      float2 qd = *(const float2*)(qrow + 2 * ec);
      float2 qu = *(const float2*)(qrow + 64 + 2 * ec);

      float2 lo, hi;
      lo.x = 0.5f * (qa[0] + qa[1]) * Sv + qd.x;
      lo.y = 0.5f * (qa[2] + qa[3]) * Sv + qd.y;
      hi.x = 0.5f * (qa[0] * sgw[0] + qa[1] * sgw[1]) + qu.x;
      hi.y = 0.5f * (qa[2] * sgw[2] + qa[3] * sgw[3]) + qu.y;

      float* orow = out + (size_t)q * DD;
      *(float2*)(orow + 2 * ec) = lo;
      *(float2*)(orow + 64 + 2 * ec) = hi;
    }
  }
}

// ---------------------------------------------------------------------------
extern "C" void kernel_launch(void* const* d_in, const int* in_sizes, int n_in,
                              void* d_out, int out_size, void* d_ws, size_t ws_size,
                              hipStream_t stream) {
  const float* sfi = (const float*)d_in[0];
  const float* sf  = (const float*)d_in[1];
  const float* qf  = (const float*)d_in[2];
  const float* W1  = (const float*)d_in[3];
  const float* b1  = (const float*)d_in[4];
  const float* W2  = (const float*)d_in[5];
  const float* b2  = (const float*)d_in[6];
  const int* slab  = (const int*)d_in[7];
  float* out = (float*)d_out;

  float* sg    = (float*)d_ws;                    // 2048 f
  short* WtTg  = (short*)(sg + CC * DD);          // 262144 shorts (512 KB)
  float* partA = (float*)(WtTg + CC * DD * DD);   // 64*2048 f
  float* partB = partA + NBLK * CC * DD;          // 64*2048 f
  float* pcnt  = partB + NBLK * CC * DD;          // 64*16 f

  centers_partial<<<NBLK, 256, 0, stream>>>(sfi, sf, slab, partA, partB, pcnt);
  build_wt_kernel<<<CC, 256, 0, stream>>>(W1, partA, partB, pcnt, sg, WtTg);
  main_kernel<<<QQ / 64, 512, 0, stream>>>(qf, WtTg, b1, W2, b2, sg, out);
}

// Round 7
// 53.913 us; speedup vs baseline: 1.5767x; 1.5767x over previous
//
#include <hip/hip_runtime.h>
#include <hip/hip_bf16.h>
#include <stdint.h>

#define DD 128
#define CC 16
#define NS 1600
#define QQ 32768
#define NBLK 64
#define PLW 65  // padded plane row width (words): 64 lanes + 1 -> bank-shifted quarters

typedef __attribute__((ext_vector_type(8))) short short8;   // 8 bf16
typedef __attribute__((ext_vector_type(4))) short short4v;  // 4 bf16
typedef __attribute__((ext_vector_type(4))) float f32x4;

__device__ inline short f2bf(float x) {
  union { float f; uint32_t u; } v; v.f = x;
  uint32_t r = (v.u + 0x7FFFu + ((v.u >> 16) & 1u)) >> 16;  // RNE
  return (short)r;
}

__device__ inline uint32_t pk2bf(float lo, float hi) {
  __hip_bfloat162 h = __float22bfloat162_rn(make_float2(lo, hi));  // lo->low16
  union { __hip_bfloat162 h2; uint32_t u; } v; v.h2 = h;
  return v.u;
}

__device__ inline float bfbits2f(uint32_t hi16bits) {  // bits already in [31:16]
  union { uint32_t u; float f; } v; v.u = hi16bits;
  return v.f;
}

// ---------------------------------------------------------------------------
// Kernel 1: fused prep. grid=320, block=256.
//  blocks [0,64):  per-block partial class sums.
//  blocks [64,320): q f32 -> bf16 conversion (qbf), coalesced.
// ---------------------------------------------------------------------------
__global__ __launch_bounds__(256) void prep_kernel(
    const float* __restrict__ sfi, const float* __restrict__ sf,
    const int* __restrict__ labels, const float* __restrict__ qf,
    float* __restrict__ partA, float* __restrict__ partB,
    float* __restrict__ pcnt, short* __restrict__ qbf) {
  const int t = threadIdx.x;

  if (blockIdx.x >= NBLK) {  // ---- q conversion: 128 rows per block ----
    const size_t cb = (size_t)(blockIdx.x - NBLK) * (128 * DD);
#pragma unroll
    for (int i = 0; i < 16; ++i) {
      const size_t off = cb + ((size_t)i * 256 + t) * 4;
      f32x4 f = *(const f32x4*)(qf + off);
      union { short4v s; uint32_t u[2]; } r;
      r.u[0] = pk2bf(f[0], f[1]);
      r.u[1] = pk2bf(f[2], f[3]);
      *(short4v*)(qbf + off) = r.s;
    }
    return;
  }

  // ---- centers partials ----
  __shared__ float accA[2][CC][DD];
  __shared__ float accB[2][CC][DD];
  __shared__ float cnt[2][CC];
  const int d = t & 127, s = t >> 7;
  for (int i = t; i < 2 * CC * DD; i += 256) {
    ((float*)accA)[i] = 0.f;
    ((float*)accB)[i] = 0.f;
  }
  if (t < 2 * CC) ((float*)cnt)[t] = 0.f;
  __syncthreads();

  const int base = blockIdx.x * (NS / NBLK);
  for (int i = s; i < NS / NBLK; i += 2) {
    const int r = base + i;
    const int lbl = labels[r];
    accA[s][lbl][d] += sfi[(size_t)r * DD + d];
    accB[s][lbl][d] += sf[(size_t)r * DD + d];
    if (d == 0) cnt[s][lbl] += 1.f;
  }
  __syncthreads();

  float* pa = partA + (size_t)blockIdx.x * (CC * DD);
  float* pb = partB + (size_t)blockIdx.x * (CC * DD);
  for (int i = t; i < CC * DD; i += 256) {
    pa[i] = ((float*)accA)[i] + ((float*)accA)[CC * DD + i];
    pb[i] = ((float*)accB)[i] + ((float*)accB)[CC * DD + i];
  }
  if (t < CC) pcnt[blockIdx.x * CC + t] = cnt[0][t] + cnt[1][t];
}

// ---------------------------------------------------------------------------
// Kernel 2: finalize centers + fused per-class weights in FRAGMENT order.
// 16B unit u within class c: u = w*256 + kb*64 + lane (w=0..7, kb=0..3)
//   holds WtT[j][e0..e0+7] bf16, j = w*16 + (lane&15), e0 = kb*32 + (lane>>4)*8
// grid=16 (c), block=256. (layout unchanged -- main depends on it)
// ---------------------------------------------------------------------------
__global__ __launch_bounds__(256) void build_wt_kernel(
    const float* __restrict__ W1, const float* __restrict__ partA,
    const float* __restrict__ partB, const float* __restrict__ pcnt,
    float* __restrict__ sg_out, short* __restrict__ WtTg) {
  __shared__ float sgc[DD], prc[DD];
  const int c = blockIdx.x, t = threadIdx.x;

  float cnt = 0.f;
  for (int b = 0; b < NBLK; ++b) cnt += pcnt[b * CC + c];
  cnt = fmaxf(cnt, 1.f);
  if (t < 128) {
    float a = 0.f;
    for (int b = 0; b < NBLK; ++b) a += partA[(size_t)b * (CC * DD) + c * DD + t];
    const float m = a / cnt;
    const float s = 1.f / (1.f + expf(-m));
    sgc[t] = s;
    sg_out[c * DD + t] = s;
  } else {
    const int d = t - 128;
    float a = 0.f;
    for (int b = 0; b < NBLK; ++b) a += partB[(size_t)b * (CC * DD) + c * DD + d];
    prc[d] = a / cnt;
  }
  __syncthreads();

  for (int it = 0; it < 8; ++it) {
    const int u = it * 256 + t;
    const int w_ = u >> 8;
    const int kb = (u >> 6) & 3;
    const int lane = u & 63;
    const int j = w_ * 16 + (lane & 15);
    const int e0 = kb * 32 + (lane >> 4) * 8;
    short8 r;
#pragma unroll
    for (int rr = 0; rr < 8; ++rr) {
      const int e = e0 + rr;
      float v = W1[e * DD + j] + sgc[e] * W1[(DD + e) * DD + j] +
                prc[e] * W1[2 * DD * DD + j];
      r[rr] = f2bf(v);
    }
    *(short8*)(WtTg + ((size_t)c * 2048 + u) * 8) = r;
  }
}

// ---------------------------------------------------------------------------
// Kernel 3: FUSED main. grid=512, block=512 (8 waves), 64 q/block, 2 blk/CU.
// Wave w: j rows [w*16,+16). Per class: 4 W loads (L2, reg-dbuf) + 16 MFMA +
// lane-local relu/W2 fold -> 4x ds_write_b32 into pad-1 qn-planes.
// REDUCE after classes 7/15: 256 thr sum (wv x l4), sigmoid -> w_lds[q][c].
// Fused agg epilogue: wave=q-slot, lane=e-pair, sgv float2[16] (32 regs),
// q from qbf (bf16, L2-warm). Loop live ~120 regs, epilogue ~60 -> no spill.
// ---------------------------------------------------------------------------
__global__ __launch_bounds__(512, 4) void main_kernel(
    const short* __restrict__ qbf, const short* __restrict__ WtTg,
    const float* __restrict__ b1, const float* __restrict__ W2,
    const float* __restrict__ b2, const float* __restrict__ sg,
    float* __restrict__ out) {
  __shared__ float p_pln[4 * 64 * PLW];  // 4 qn-planes x 64 (c7,w)-slots x 65
  __shared__ float w_lds[64][17];        // [q][c], padded

  const int tid = threadIdx.x;
  const int lane = tid & 63;
  const int w = tid >> 6;  // 0..7
  const int l15 = lane & 15, l4 = lane >> 4;
  const int qbase = blockIdx.x * 64;

  // ---- B fragments: direct bf16 loads ----
  short8 bq[4][4];
#pragma unroll
  for (int qn = 0; qn < 4; ++qn) {
    const short* qrow = qbf + (size_t)(qbase + qn * 16 + l15) * DD;
#pragma unroll
    for (int kb = 0; kb < 4; ++kb)
      bq[qn][kb] = *(const short8*)(qrow + kb * 32 + l4 * 8);
  }

  const f32x4 b1v = *(const f32x4*)(b1 + w * 16 + l4 * 4);
  const f32x4 w2v = *(const f32x4*)(W2 + w * 16 + l4 * 4);
  const float b2s = b2[0];

  const char* wbase = (const char*)WtTg + w * 4096 + lane * 16;

#define LOADW(dst, cls)                                                     \
  {                                                                         \
    _Pragma("unroll") for (int kb = 0; kb < 4; ++kb) dst[kb] =              \
        *(const short8*)(wbase + (size_t)(cls)*32768 + kb * 1024);          \
  }

#define COMPUTE(wf, cls)                                                    \
  {                                                                         \
    const int slot = (((cls)&7) * 8 + w) * PLW + lane;                      \
    _Pragma("unroll") for (int qp = 0; qp < 2; ++qp) {                      \
      f32x4 a0 = b1v, a1 = b1v;                                             \
      _Pragma("unroll") for (int kb = 0; kb < 4; ++kb) {                    \
        a0 = __builtin_amdgcn_mfma_f32_16x16x32_bf16(wf[kb],                \
                                                     bq[2 * qp][kb], a0,    \
                                                     0, 0, 0);              \
        a1 = __builtin_amdgcn_mfma_f32_16x16x32_bf16(wf[kb],                \
                                                     bq[2 * qp + 1][kb],    \
                                                     a1, 0, 0, 0);          \
      }                                                                     \
      float p0 = 0.f, p1 = 0.f;                                             \
      _Pragma("unroll") for (int i = 0; i < 4; ++i) {                       \
        p0 += fmaxf(a0[i], 0.f) * w2v[i];                                   \
        p1 += fmaxf(a1[i], 0.f) * w2v[i];                                   \
      }                                                                     \
      p_pln[(2 * qp) * (64 * PLW) + slot] = p0;                             \
      p_pln[(2 * qp + 1) * (64 * PLW) + slot] = p1;                         \
    }                                                                       \
  }

  // REDUCE one 8-class half: 256 threads, sum over (wv x l4), sigmoid.
#define REDUCE(hf)                                                          \
  {                                                                         \
    __syncthreads();                                                        \
    if (tid < 256) {                                                        \
      const int qp = tid >> 7, c7 = (tid >> 4) & 7, lr = tid & 15;          \
      _Pragma("unroll") for (int qq = 0; qq < 2; ++qq) {                    \
        const int qn = qp * 2 + qq;                                         \
        const float* pb = p_pln + qn * (64 * PLW) + c7 * (8 * PLW) + lr;    \
        float sacc = 0.f;                                                   \
        _Pragma("unroll") for (int wv = 0; wv < 8; ++wv)                    \
            _Pragma("unroll") for (int g = 0; g < 4; ++g) sacc +=           \
            pb[wv * PLW + g * 16];                                          \
        w_lds[qn * 16 + lr][(hf)*8 + c7] =                                  \
            1.f / (1.f + __expf(-(sacc + b2s)));                            \
      }                                                                     \
    }                                                                       \
    __syncthreads();                                                        \
  }

  short8 wfA[4], wfB[4];
  LOADW(wfA, 0);
  for (int cp = 0; cp < CC; cp += 2) {
    LOADW(wfB, cp + 1);
    COMPUTE(wfA, cp);
    if (cp + 2 < CC) LOADW(wfA, cp + 2);
    COMPUTE(wfB, cp + 1);
    if (cp == 6) REDUCE(0);
    if (cp == 14) REDUCE(1);
  }
#undef LOADW
#undef COMPUTE
#undef REDUCE

  // ---- fused agg epilogue: wave w -> q-slots qi*8+w, lane -> e-pair ----
  {
    float2 sgv[16];  // 32 regs
#pragma unroll
    for (int c = 0; c < 16; ++c)
      sgv[c] = *(const float2*)(sg + c * DD + 2 * lane);

#pragma unroll
    for (int qi = 0; qi < 8; ++qi) {
      const int ql = qi * 8 + w;
      const int q = qbase + ql;
      float Sv = 0.f, swx = 0.f, swy = 0.f;
#pragma unroll
      for (int c = 0; c < 16; ++c) {
        const float wc = w_lds[ql][c];  // broadcast (uniform addr per wave)
        Sv += wc;
        swx += wc * sgv[c].x;
        swy += wc * sgv[c].y;
      }
      const uint16_t* row = (const uint16_t*)(qbf + (size_t)q * DD);
      const uint32_t pair = *(const uint32_t*)(row + 2 * lane);
      const float q0 = bfbits2f(pair << 16);          // row[2*lane]
      const float q1 = bfbits2f(pair & 0xFFFF0000u);  // row[2*lane+1]
      const float qlo = bfbits2f((uint32_t)row[lane] << 16);
      const float qhi = bfbits2f((uint32_t)row[64 + lane] << 16);

      float* orow = out + (size_t)q * DD;
      orow[lane] = 0.5f * (q0 + q1) * Sv + qlo;
      orow[64 + lane] = 0.5f * (q0 * swx + q1 * swy) + qhi;
    }
  }
}

// ---------------------------------------------------------------------------
extern "C" void kernel_launch(void* const* d_in, const int* in_sizes, int n_in,
                              void* d_out, int out_size, void* d_ws, size_t ws_size,
                              hipStream_t stream) {
  const float* sfi = (const float*)d_in[0];
  const float* sf  = (const float*)d_in[1];
  const float* qf  = (const float*)d_in[2];
  const float* W1  = (const float*)d_in[3];
  const float* b1  = (const float*)d_in[4];
  const float* W2  = (const float*)d_in[5];
  const float* b2  = (const float*)d_in[6];
  const int* slab  = (const int*)d_in[7];
  float* out = (float*)d_out;

  float* sg    = (float*)d_ws;                    // 2048 f
  short* WtTg  = (short*)(sg + CC * DD);          // 262144 shorts (512 KB)
  float* partA = (float*)(WtTg + CC * DD * DD);   // 64*2048 f
  float* partB = partA + NBLK * CC * DD;          // 64*2048 f
  float* pcnt  = partB + NBLK * CC * DD;          // 64*16 f
  short* qbf   = (short*)(pcnt + NBLK * CC);      // QQ*DD shorts (8 MB)

  prep_kernel<<<NBLK + QQ / 128, 256, 0, stream>>>(sfi, sf, slab, qf, partA,
                                                   partB, pcnt, qbf);
  build_wt_kernel<<<CC, 256, 0, stream>>>(W1, partA, partB, pcnt, sg, WtTg);
  main_kernel<<<QQ / 64, 512, 0, stream>>>(qbf, WtTg, b1, W2, b2, sg, out);
}